// Round 15
// baseline (296.219 us; speedup 1.0000x reference)
//
#include <hip/hip_runtime.h>

#define NUSER 30000
#define NITEM 50000
#define NN    80000
#define NE    1200000
#define DD    64
#define FEAT  512
#define HIDN  256
#define MPAD  50048           // NITEM rounded up to 128 (grid sizing)

#define NBUCK  625            // dst >> 7 ; 625*128 == 80000 exactly
#define NCHUNK 256            // edge chunks for histogram/binscat
#define CHSZ   ((NE + NCHUNK - 1) / NCHUNK)   // 4688
#define NHIST  (NBUCK * NCHUNK)               // 160000
#define NPART  ((NHIST + 1023) / 1024)        // 157
#define CSRCAP (NE + 1024 * NBUCK)            // fixed-capacity bucket layout (1.84M)

#define G1_BLOCKS  (MPAD / 64)                // 782 (BM=64, BN=256 full width)
#define G2_BLOCKS  (MPAD / 128)               // 391
#define CVTW_BLOCKS ((HIDN * FEAT / 4 + DD * HIDN / 4 + DD * DD / 4) / 256) // 148

using s16x8 = __attribute__((ext_vector_type(8))) short;
using f32x4 = __attribute__((ext_vector_type(4))) float;
using u32x4 = __attribute__((ext_vector_type(4))) unsigned int;

__device__ __forceinline__ unsigned short f2bf(float f){
  unsigned int u = __float_as_uint(f);
  unsigned int r = (u + 0x7fffu + ((u >> 16) & 1u)) >> 16;
  return (unsigned short)r;
}

__device__ __forceinline__ float bf2f(unsigned short s){
  unsigned int u = ((unsigned int)s) << 16;
  return __uint_as_float(u);
}

// packed f32x2 -> bf16x2 (RNE), gfx950 HW cvt [T12/m240]
__device__ __forceinline__ unsigned int cvtpk(float lo, float hi){
  unsigned int r;
  asm("v_cvt_pk_bf16_f32 %0, %1, %2" : "=v"(r) : "v"(lo), "v"(hi));
  return r;
}

__device__ __forceinline__ void gload_lds16(const void* g, void* l){
  __builtin_amdgcn_global_load_lds(
      (const __attribute__((address_space(1))) unsigned int*)g,
      (__attribute__((address_space(3))) unsigned int*)l, 16, 0, 0);
}

// ================= device bodies (packed kernels call these) =================

// ---- histo: per-chunk LDS histogram over 625 dst-buckets ----
__device__ __forceinline__ void dev_histo(int c, const int* __restrict__ ei,
                                          int* __restrict__ hist, int* h){
  const int tid = threadIdx.x;
  for (int i = tid; i < NBUCK; i += 256) h[i] = 0;
  __syncthreads();
  int e0 = c * CHSZ, e1 = min(e0 + CHSZ, NE);
  for (int e = e0 + tid; e < e1; e += 256)
    atomicAdd(&h[ei[NE + e] >> 7], 1);
  __syncthreads();
  for (int i = tid; i < NBUCK; i += 256) hist[i * NCHUNK + c] = h[i];
}

// ---- weights fp32 -> bf16 (w1 | w2 | cw only; feats stays f32) ----
__device__ __forceinline__ void dev_cvtw(int blk,
    const float* __restrict__ w1, const float* __restrict__ w2, const float* __restrict__ cw,
    unsigned short* __restrict__ w1b, unsigned short* __restrict__ w2b,
    unsigned short* __restrict__ cwb){
  const int n1 = HIDN * FEAT / 4, n2 = DD * HIDN / 4, n3 = DD * DD / 4;
  int q = blk * 256 + threadIdx.x;
  const float4* src; ushort4* dst; int i;
  if (q < n1){ src = (const float4*)w1; dst = (ushort4*)w1b; i = q; }
  else if (q < n1 + n2){ src = (const float4*)w2; dst = (ushort4*)w2b; i = q - n1; }
  else if (q < n1 + n2 + n3){ src = (const float4*)cw; dst = (ushort4*)cwb; i = q - n1 - n2; }
  else return;
  float4 v = src[i];
  ushort4 o = { f2bf(v.x), f2bf(v.y), f2bf(v.z), f2bf(v.w) };
  dst[i] = o;
}

// ---- GEMM1 (zero-barrier): hiddenb = bf16(leaky(feats @ w1b^T + b1)) ----
// BM=64 (4 waves x 16 rows), BN=256. A streamed into registers (f32, cvt_pk->bf16);
// B fragments read DIRECTLY from global (w1b = 256KB, L2/L3-resident, broadcast).
// No LDS, no __syncthreads, no vmcnt drains -- pure ILP/TLP pipelining.
__device__ __forceinline__ void dev_gemm1(int by,
    const float* __restrict__ feats, const short* __restrict__ w1b,
    const float* __restrict__ b1, unsigned short* __restrict__ hiddenb){
  const int tid  = threadIdx.x;
  const int wid  = tid >> 6;
  const int lane = tid & 63;
  const int r    = lane & 15;           // A row within wave tile / B row within 16-group
  const int ks   = lane >> 4;           // k-slot (0..3) -> 8 elems
  const int m0   = by * 64 + wid * 16;  // wave's 16-row tile

  int arow = m0 + r; if (arow >= NITEM) arow = NITEM - 1;   // clamp (stores masked)
  const float* ap = feats + (size_t)arow * FEAT + ks * 8;
  const short* bp = w1b + (size_t)r * FEAT + ks * 8;

  // ---- stream ALL A-fragments into registers (2 bursts of 8 K-steps) ----
  s16x8 afr[16];
  {
    float4 av[16];
    #pragma unroll
    for (int t = 0; t < 8; t++){
      av[t * 2 + 0] = *(const float4*)(ap + t * 32);
      av[t * 2 + 1] = *(const float4*)(ap + t * 32 + 4);
    }
    #pragma unroll
    for (int t = 0; t < 8; t++){
      u32x4 u;
      u[0] = cvtpk(av[t*2].x,   av[t*2].y);   u[1] = cvtpk(av[t*2].z,   av[t*2].w);
      u[2] = cvtpk(av[t*2+1].x, av[t*2+1].y); u[3] = cvtpk(av[t*2+1].z, av[t*2+1].w);
      afr[t] = *(s16x8*)&u;
    }
    #pragma unroll
    for (int t = 0; t < 8; t++){
      av[t * 2 + 0] = *(const float4*)(ap + (t + 8) * 32);
      av[t * 2 + 1] = *(const float4*)(ap + (t + 8) * 32 + 4);
    }
    #pragma unroll
    for (int t = 0; t < 8; t++){
      u32x4 u;
      u[0] = cvtpk(av[t*2].x,   av[t*2].y);   u[1] = cvtpk(av[t*2].z,   av[t*2].w);
      u[2] = cvtpk(av[t*2+1].x, av[t*2+1].y); u[3] = cvtpk(av[t*2+1].z, av[t*2+1].w);
      afr[t + 8] = *(s16x8*)&u;
    }
  }

  f32x4 acc[16] = {};

  // ---- K-loop: B frags straight from L2; 16 independent MFMA chains ----
  #pragma unroll
  for (int t = 0; t < 16; t++){
    #pragma unroll
    for (int n = 0; n < 16; n++){
      s16x8 bf = *(const s16x8*)(bp + (size_t)n * 16 * FEAT + t * 32);
      acc[n] = __builtin_amdgcn_mfma_f32_16x16x32_bf16(afr[t], bf, acc[n], 0, 0, 0);
    }
  }

  // ---- epilogue: bias + leaky -> bf16 (C/D: col=lane&15, row=(lane>>4)*4+rr) ----
  #pragma unroll
  for (int n = 0; n < 16; n++){
    int col = n * 16 + r;
    float bi = b1[col];
    #pragma unroll
    for (int rr = 0; rr < 4; rr++){
      int row = m0 + ks * 4 + rr;
      if (row >= NITEM) continue;
      float v = acc[n][rr] + bi;
      v = v > 0.f ? v : 0.01f * v;
      hiddenb[(size_t)row * HIDN + col] = f2bf(v);
    }
  }
}

// ---- scan_apply, 256-thread version (4 elems/thread) ----
__device__ __forceinline__ void dev_scan_apply4(int blk, const int* __restrict__ a,
                                                const int* __restrict__ boff,
                                                int* __restrict__ sc, int* wsum4){
  int tid = threadIdx.x;
  int base = blk * 1024 + tid * 4;
  int v0 = (base + 0 < NHIST) ? a[base + 0] : 0;
  int v1 = (base + 1 < NHIST) ? a[base + 1] : 0;
  int v2 = (base + 2 < NHIST) ? a[base + 2] : 0;
  int v3 = (base + 3 < NHIST) ? a[base + 3] : 0;
  int s = v0 + v1 + v2 + v3;
  int lane = tid & 63, w = tid >> 6;
  int incl = s;
  #pragma unroll
  for (int o = 1; o < 64; o <<= 1){ int u = __shfl_up(incl, o); if (lane >= o) incl += u; }
  if (lane == 63) wsum4[w] = incl;
  __syncthreads();
  int woff = 0;
  #pragma unroll
  for (int k = 0; k < 4; k++) if (k < w) woff += wsum4[k];
  int excl = boff[blk] + woff + incl - s;
  if (base + 0 < NHIST) sc[base + 0] = excl; excl += v0;
  if (base + 1 < NHIST) sc[base + 1] = excl; excl += v1;
  if (base + 2 < NHIST) sc[base + 2] = excl; excl += v2;
  if (base + 3 < NHIST) sc[base + 3] = excl;
}

// ---- GEMM2: x items = hiddenb @ w2b^T + b2 (f32 out) ----
__device__ __forceinline__ void dev_gemm2(int by,
    const short* __restrict__ Ag, const short* __restrict__ Bg,
    const float* __restrict__ bias, float* __restrict__ Cout,
    short* As, short* Bs){
  const int tid  = threadIdx.x;
  const int wid  = tid >> 6;
  const int lane = tid & 63;
  const int wr   = wid >> 1;
  const int wc   = wid & 1;
  const int m0   = by * 128;

  f32x4 acc[4][2] = {};

  for (int k0 = 0; k0 < HIDN; k0 += 32){
    #pragma unroll
    for (int s = 0; s < 2; s++){
      int q = s * 256 + tid;
      int row = q >> 2, kc = q & 3;
      const short* src = Ag + (size_t)(m0 + row) * HIDN + k0 + kc * 8;
      gload_lds16(src, As + (size_t)(s * 256 + wid * 64) * 8);
    }
    {
      int row = tid >> 2, kc = tid & 3;
      const short* src = Bg + (size_t)row * HIDN + k0 + kc * 8;
      gload_lds16(src, Bs + (size_t)(wid * 64) * 8);
    }
    __syncthreads();

    s16x8 af[4], bf[2];
    #pragma unroll
    for (int m = 0; m < 4; m++)
      af[m] = *(const s16x8*)&As[(wr * 64 + m * 16 + (lane & 15)) * 32 + (lane >> 4) * 8];
    #pragma unroll
    for (int n = 0; n < 2; n++)
      bf[n] = *(const s16x8*)&Bs[(wc * 32 + n * 16 + (lane & 15)) * 32 + (lane >> 4) * 8];
    #pragma unroll
    for (int m = 0; m < 4; m++)
      #pragma unroll
      for (int n = 0; n < 2; n++)
        acc[m][n] = __builtin_amdgcn_mfma_f32_16x16x32_bf16(af[m], bf[n], acc[m][n], 0, 0, 0);
    __syncthreads();
  }

  #pragma unroll
  for (int m = 0; m < 4; m++){
    int row_base = m0 + wr * 64 + m * 16 + (lane >> 4) * 4;
    #pragma unroll
    for (int n = 0; n < 2; n++){
      int col = wc * 32 + n * 16 + (lane & 15);
      float bi = bias[col];
      #pragma unroll
      for (int r = 0; r < 4; r++){
        int row = row_base + r;
        if (row >= NITEM) continue;
        Cout[(size_t)row * DD + col] = acc[m][n][r] + bi;
      }
    }
  }
}

// ---- binscat: LDS-cursor scatter of packed (dst&127)<<17 | src ----
__device__ __forceinline__ void dev_binscat(int c, const int* __restrict__ ei,
                                            const int* __restrict__ sc,
                                            int* __restrict__ pairsv, int* cur){
  const int tid = threadIdx.x;
  for (int i = tid; i < NBUCK; i += 256) cur[i] = sc[i * NCHUNK + c];
  __syncthreads();
  int e0 = c * CHSZ, e1 = min(e0 + CHSZ, NE);
  for (int e = e0 + tid; e < e1; e += 256){
    int s = ei[e];
    int d = ei[NE + e];
    int pos = atomicAdd(&cur[d >> 7], 1);
    pairsv[pos] = ((d & 127) << 17) | s;
  }
}

// ---- bucketize (fused count + scan + fill): fixed base = sc[b*NCHUNK] + 1024*b ----
__device__ __forceinline__ void dev_bucketize(int b,
    const int* __restrict__ pairsv, const int* __restrict__ sc,
    float* __restrict__ dinv, int* __restrict__ csr,
    int* __restrict__ indptr, int* __restrict__ nitv,
    int* cnt, int* cur, int* l0, int* wtot){
  const int tid = threadIdx.x;
  if (tid < 128) cnt[tid] = 0;
  __syncthreads();
  int e0 = sc[b * NCHUNK];
  int e1 = (b == NBUCK - 1) ? NE : sc[(b + 1) * NCHUNK];
  for (int e = e0 + tid; e < e1; e += 256)
    atomicAdd(&cnt[(pairsv[e] >> 17) & 127], 1);
  __syncthreads();
  int lane = tid & 63;
  int incl = 0, pc = 0, cdeg = 0;
  if (tid < 128){
    cdeg = cnt[tid];
    pc = (cdeg + 8) & ~7;            // deg + 1 self, padded to x8
    incl = pc;
    #pragma unroll
    for (int o = 1; o < 64; o <<= 1){ int u = __shfl_up(incl, o); if (lane >= o) incl += u; }
  }
  if (tid == 63) *wtot = incl;
  __syncthreads();
  if (tid < 128){
    int excl = incl - pc + (tid >= 64 ? *wtot : 0);
    cur[tid] = excl; l0[tid] = excl;
    dinv[b * 128 + tid] = rsqrtf((float)(cdeg + 1));
  }
  __syncthreads();
  const int base = e0 + 1024 * b;
  for (int e = e0 + tid; e < e1; e += 256){
    int v = pairsv[e];
    int li = (v >> 17) & 127;
    int p = atomicAdd(&cur[li], 1);
    csr[base + p] = v & 0x1FFFF;
  }
  __syncthreads();
  if (tid < 128){
    int node = b * 128 + tid;
    int c = cur[tid];                 // l0 + deg
    int l = l0[tid];
    int end = l + ((c - l + 8) & ~7);
    csr[base + c] = node;             // self-loop
    for (int q = c + 1; q < end; q++) csr[base + q] = NN;   // pads -> zero row
    indptr[node] = base + l;
    nitv[node] = (end - l) >> 3;      // padded count / 8
  }
}

// ---- normalize one 4-node block ----
__device__ __forceinline__ void dev_normalize(int nb, const float* __restrict__ pref,
                                              float* __restrict__ x){
  int node = nb * 4 + (threadIdx.x >> 6);
  int lane = threadIdx.x & 63;
  float v = (node < NUSER) ? pref[(size_t)node * DD + lane] : x[(size_t)node * DD + lane];
  float ss = v * v;
  #pragma unroll
  for (int o = 1; o < 64; o <<= 1) ss += __shfl_xor(ss, o);
  v = v / fmaxf(sqrtf(ss), 1e-12f);
  x[(size_t)node * DD + lane] = v;
}

// ================= packed kernels =================
__global__ __launch_bounds__(256) void p1_histo_cvtw(const int* __restrict__ ei,
    int* __restrict__ hist, const float* __restrict__ w1, const float* __restrict__ w2,
    const float* __restrict__ cw, unsigned short* __restrict__ w1b,
    unsigned short* __restrict__ w2b, unsigned short* __restrict__ cwb){
  __shared__ int h[NBUCK];
  int b = blockIdx.x;
  if (b < NCHUNK) dev_histo(b, ei, hist, h);
  else            dev_cvtw(b - NCHUNK, w1, w2, cw, w1b, w2b, cwb);
}

__global__ __launch_bounds__(256) void scan_part(const int* __restrict__ a,
                                                 int* __restrict__ bsum){
  __shared__ int ws4[4];
  int b = blockIdx.x, base = b * 1024;
  int v = 0;
  #pragma unroll
  for (int s = 0; s < 4; s++){
    int idx = base + s * 256 + threadIdx.x;
    if (idx < NHIST) v += a[idx];
  }
  int lane = threadIdx.x & 63, w = threadIdx.x >> 6;
  #pragma unroll
  for (int o = 1; o < 64; o <<= 1) v += __shfl_xor(v, o);
  if (lane == 0) ws4[w] = v;
  __syncthreads();
  if (threadIdx.x == 0) bsum[b] = ws4[0] + ws4[1] + ws4[2] + ws4[3];
}

__global__ __launch_bounds__(1024) void scan_mid(const int* __restrict__ a,
                                                 int* __restrict__ excl_out){
  __shared__ int wsum[16];
  int tid = threadIdx.x;
  int v = (tid < NPART) ? a[tid] : 0;
  int lane = tid & 63, w = tid >> 6;
  int incl = v;
  #pragma unroll
  for (int o = 1; o < 64; o <<= 1){ int u = __shfl_up(incl, o); if (lane >= o) incl += u; }
  if (lane == 63) wsum[w] = incl;
  __syncthreads();
  int woff = 0;
  #pragma unroll
  for (int k = 0; k < 16; k++) if (k < w) woff += wsum[k];
  if (tid < NPART) excl_out[tid] = woff + incl - v;
}

__global__ __launch_bounds__(256) void p2_gemm1_scan(const float* __restrict__ feats,
    const short* __restrict__ w1b, const float* __restrict__ b1,
    unsigned short* __restrict__ hiddenb, const int* __restrict__ hist,
    const int* __restrict__ boff, int* __restrict__ sc){
  __shared__ int wsum4[4];
  int b = blockIdx.x;
  if (b < G1_BLOCKS) dev_gemm1(b, feats, w1b, b1, hiddenb);
  else               dev_scan_apply4(b - G1_BLOCKS, hist, boff, sc, wsum4);
}

__global__ __launch_bounds__(256) void p3_gemm2_binscat(const unsigned short* __restrict__ hiddenb,
    const short* __restrict__ w2b, const float* __restrict__ b2, float* __restrict__ xitems,
    const int* __restrict__ ei, const int* __restrict__ sc, int* __restrict__ pairsv){
  __shared__ __align__(16) short As[128 * 32];    // 8KB
  __shared__ __align__(16) short Bs[64 * 32];     // 4KB
  __shared__ int cur[NBUCK];                      // 2.5KB
  int b = blockIdx.x;
  if (b < G2_BLOCKS) dev_gemm2(b, (const short*)hiddenb, w2b, b2, xitems, As, Bs);
  else               dev_binscat(b - G2_BLOCKS, ei, sc, pairsv, cur);
}

__global__ __launch_bounds__(256) void p4_bucketize_norm(const int* __restrict__ pairsv,
    const int* __restrict__ sc, float* __restrict__ dinv, int* __restrict__ csr,
    int* __restrict__ indptr, int* __restrict__ nitv,
    const float* __restrict__ pref, float* __restrict__ x){
  __shared__ int cnt[128], cur[128], l0[128];
  __shared__ int wtot;
  int b = blockIdx.x;
  if (b < NBUCK) dev_bucketize(b, pairsv, sc, dinv, csr, indptr, nitv, cnt, cur, l0, &wtot);
  else           dev_normalize(b - NBUCK, pref, x);
}

// ---------------- lin via MFMA: hsb = bf16(dinv[row] * (src @ cwb^T)) ----------------
// block 0 additionally zeroes the pad row hsb[NN] (replaces a memset launch).
__global__ __launch_bounds__(256) void lin_mfma(const float* __restrict__ src,
                                                const short* __restrict__ cwb,
                                                const float* __restrict__ dinv,
                                                unsigned short* __restrict__ hsb){
  constexpr int AP = 72;                        // padded stride (elems)
  __shared__ __align__(16) short As[128 * AP];  // 18KB

  const int tid  = threadIdx.x;
  const int wid  = tid >> 6;
  const int lane = tid & 63;
  const int wr   = wid >> 1;
  const int wc   = wid & 1;
  const int m0   = blockIdx.x * 128;

  if (blockIdx.x == 0 && tid < 16)
    *(unsigned long long*)&hsb[(size_t)NN * DD + tid * 4] = 0ULL;  // 128B pad row

  #pragma unroll
  for (int s = 0; s < 8; s++){
    int c = s * 256 + tid;
    int row = c >> 4, kc = c & 15;
    float4 v = *(const float4*)&src[(size_t)(m0 + row) * DD + kc * 4];
    ushort4 o = { f2bf(v.x), f2bf(v.y), f2bf(v.z), f2bf(v.w) };
    *(ushort4*)&As[row * AP + kc * 4] = o;
  }
  __syncthreads();

  f32x4 acc[4][2] = {};
  #pragma unroll
  for (int kk = 0; kk < DD; kk += 32){
    s16x8 af[4], bf[2];
    #pragma unroll
    for (int m = 0; m < 4; m++)
      af[m] = *(const s16x8*)&As[(wr * 64 + m * 16 + (lane & 15)) * AP + kk + (lane >> 4) * 8];
    #pragma unroll
    for (int n = 0; n < 2; n++)
      bf[n] = *(const s16x8*)&cwb[(size_t)(wc * 32 + n * 16 + (lane & 15)) * DD + kk + (lane >> 4) * 8];
    #pragma unroll
    for (int m = 0; m < 4; m++)
      #pragma unroll
      for (int n = 0; n < 2; n++)
        acc[m][n] = __builtin_amdgcn_mfma_f32_16x16x32_bf16(af[m], bf[n], acc[m][n], 0, 0, 0);
  }

  #pragma unroll
  for (int m = 0; m < 4; m++){
    int row_base = m0 + wr * 64 + m * 16 + (lane >> 4) * 4;
    #pragma unroll
    for (int n = 0; n < 2; n++){
      int col = wc * 32 + n * 16 + (lane & 15);
      #pragma unroll
      for (int r = 0; r < 4; r++){
        int row = row_base + r;
        hsb[(size_t)row * DD + col] = f2bf(dinv[row] * acc[m][n][r]);
      }
    }
  }
}

// ---------------- gather aggregation: 8 edges in flight, 8 lanes x s16x8 ----------------
template<int FINAL>
__global__ __launch_bounds__(256) void agg_kernel(const unsigned short* __restrict__ hsb,
                                                  const float* __restrict__ dinv,
                                                  const int* __restrict__ indptr,
                                                  const int* __restrict__ nitv,
                                                  const int* __restrict__ csr,
                                                  const float* __restrict__ bias,
                                                  const float* __restrict__ x,
                                                  const float* __restrict__ h,
                                                  float* __restrict__ out,
                                                  const float* __restrict__ pref,
                                                  float* __restrict__ out2){
  int b = blockIdx.x;
  if (FINAL && b >= NN / 4){
    long q = (long)(b - NN / 4) * 256 + threadIdx.x;
    if (q < (long)NUSER * DD / 4)
      ((float4*)out2)[q] = ((const float4*)pref)[q];
    return;
  }
  int node = b * 4 + (threadIdx.x >> 6);
  int lane = threadIdx.x & 63;
  int g  = lane >> 3;
  int sl = lane & 7;
  int e0 = indptr[node];
  int nit = nitv[node];
  float a0=0.f,a1=0.f,a2=0.f,a3=0.f,a4=0.f,a5=0.f,a6=0.f,a7=0.f;
  int k = e0 + g;
  for (int i = 0; i < nit; i++){
    int j = csr[k];
    k += 8;
    s16x8 v = *(const s16x8*)&hsb[(size_t)j * DD + sl * 8];
    a0 += bf2f((unsigned short)v[0]); a1 += bf2f((unsigned short)v[1]);
    a2 += bf2f((unsigned short)v[2]); a3 += bf2f((unsigned short)v[3]);
    a4 += bf2f((unsigned short)v[4]); a5 += bf2f((unsigned short)v[5]);
    a6 += bf2f((unsigned short)v[6]); a7 += bf2f((unsigned short)v[7]);
  }
  #pragma unroll
  for (int off = 8; off < 64; off <<= 1){
    a0 += __shfl_xor(a0, off); a1 += __shfl_xor(a1, off);
    a2 += __shfl_xor(a2, off); a3 += __shfl_xor(a3, off);
    a4 += __shfl_xor(a4, off); a5 += __shfl_xor(a5, off);
    a6 += __shfl_xor(a6, off); a7 += __shfl_xor(a7, off);
  }
  if (g == 0){
    float di = dinv[node];
    size_t rb = (size_t)node * DD + sl * 8;
    const float4 bi0 = *(const float4*)&bias[sl * 8];
    const float4 bi1 = *(const float4*)&bias[sl * 8 + 4];
    float4 r0, r1;
    r0.x = fmaf(di, a0, bi0.x); r0.y = fmaf(di, a1, bi0.y);
    r0.z = fmaf(di, a2, bi0.z); r0.w = fmaf(di, a3, bi0.w);
    r1.x = fmaf(di, a4, bi1.x); r1.y = fmaf(di, a5, bi1.y);
    r1.z = fmaf(di, a6, bi1.z); r1.w = fmaf(di, a7, bi1.w);
    if (FINAL){
      const float4 xv0 = *(const float4*)&x[rb];
      const float4 xv1 = *(const float4*)&x[rb + 4];
      const float4 hv0 = *(const float4*)&h[rb];
      const float4 hv1 = *(const float4*)&h[rb + 4];
      r0.x += xv0.x + hv0.x; r0.y += xv0.y + hv0.y;
      r0.z += xv0.z + hv0.z; r0.w += xv0.w + hv0.w;
      r1.x += xv1.x + hv1.x; r1.y += xv1.y + hv1.y;
      r1.z += xv1.z + hv1.z; r1.w += xv1.w + hv1.w;
    }
    *(float4*)&out[rb] = r0;
    *(float4*)&out[rb + 4] = r1;
  }
}

extern "C" void kernel_launch(void* const* d_in, const int* in_sizes, int n_in,
                              void* d_out, int out_size, void* d_ws, size_t ws_size,
                              hipStream_t stream){
  const int*   ei    = (const int*)  d_in[0];
  const float* feats = (const float*)d_in[1];
  const float* pref  = (const float*)d_in[2];
  const float* w1    = (const float*)d_in[3];
  const float* b1    = (const float*)d_in[4];
  const float* w2    = (const float*)d_in[5];
  const float* b2    = (const float*)d_in[6];
  const float* cw    = (const float*)d_in[7];
  const float* cb    = (const float*)d_in[8];
  float* out = (float*)d_out;

  // ---- workspace layout (lifetime-overlapped; peak ~77.2MB, proven) ----
  char* wsb = (char*)d_ws;
  float* x       = (float*)wsb;
  float* hbuf    = (float*)(wsb + (size_t)NN * DD * 4);
  int*   pairsv  = (int*)hbuf;
  int*   hist    = pairsv + NE;
  int*   sc      = hist + NHIST;
  int*   bsum    = sc + NHIST;
  int*   boff    = bsum + NPART;
  char*  graphb  = wsb + (size_t)NN * DD * 8;
  int*   csr     = (int*)graphb;
  int*   indptr  = csr + CSRCAP;
  int*   nitv    = indptr + NN;
  float* dinv    = (float*)(nitv + NN);
  unsigned short* hiddenb = (unsigned short*)(wsb + (size_t)MPAD * FEAT * 2);
  unsigned short* hsba = hiddenb;
  unsigned short* hsbb = hsba + (size_t)(NN + 1) * DD;
  short* w1b     = (short*)(wsb + (size_t)MPAD * FEAT * 2 + (size_t)(MPAD + 64) * HIDN * 2);
  short* w2b     = w1b + (size_t)HIDN * FEAT;
  short* cwb     = w2b + (size_t)DD * HIDN;

  // ---- P1: edge histogram ∪ weight cvt ----
  p1_histo_cvtw<<<NCHUNK + CVTW_BLOCKS, 256, 0, stream>>>(
      ei, hist, w1, w2, cw, (unsigned short*)w1b, (unsigned short*)w2b,
      (unsigned short*)cwb);
  // ---- hist scan (part -> mid) ----
  scan_part<<<NPART, 256, 0, stream>>>(hist, bsum);
  scan_mid<<<1, 1024, 0, stream>>>(bsum, boff);
  // ---- P2: GEMM1 (zero-barrier, A-in-reg, B-from-L2) ∪ scan_apply ----
  p2_gemm1_scan<<<G1_BLOCKS + NPART, 256, 0, stream>>>(
      feats, w1b, b1, hiddenb, hist, boff, sc);
  // ---- P3: GEMM2 ∪ binscat ----
  p3_gemm2_binscat<<<G2_BLOCKS + NCHUNK, 256, 0, stream>>>(
      hiddenb, w2b, b2, x + (size_t)NUSER * DD, ei, sc, pairsv);
  // ---- P4: bucketize (fused count+scan+fill) ∪ normalize ----
  p4_bucketize_norm<<<NBUCK + NN / 4, 256, 0, stream>>>(
      pairsv, sc, dinv, csr, indptr, nitv, pref, x);

  // ---- conv1: lin (+ zero hsba pad row) + gather ----
  lin_mfma<<<NN / 128, 256, 0, stream>>>(x, cwb, dinv, hsba);
  agg_kernel<0><<<NN / 4, 256, 0, stream>>>(hsba, dinv, indptr, nitv, csr, cb,
                                            nullptr, nullptr, hbuf, nullptr, nullptr);
  // ---- conv2: lin (+ zero hsbb pad row) + gather + residual + pref tail ----
  lin_mfma<<<NN / 128, 256, 0, stream>>>(hbuf, cwb, dinv, hsbb);
  agg_kernel<1><<<NN / 4 + (NUSER * DD / 4) / 256, 256, 0, stream>>>(
      hsbb, dinv, indptr, nitv, csr, cb, x, hbuf, out, pref, out + (size_t)NN * DD);
}

// Round 16
// 194.127 us; speedup vs baseline: 1.5259x; 1.5259x over previous
//
#include <hip/hip_runtime.h>

#define NUSER 30000
#define NITEM 50000
#define NN    80000
#define NE    1200000
#define DD    64
#define FEAT  512
#define HIDN  256
#define MPAD  50048           // NITEM rounded up to 128 (grid sizing)

#define NBUCK  625            // dst >> 7 ; 625*128 == 80000 exactly
#define NCHUNK 256            // edge chunks for histogram/binscat
#define CHSZ   ((NE + NCHUNK - 1) / NCHUNK)   // 4688
#define NHIST  (NBUCK * NCHUNK)               // 160000
#define NPART  ((NHIST + 1023) / 1024)        // 157
#define CSRCAP (NE + 1024 * NBUCK)            // fixed-capacity bucket layout (1.84M)

#define G1_BLOCKS  (2 * (MPAD / 64))          // 1564 (bx in 0..1, by in 0..781; BM=64)
#define G2_BLOCKS  (MPAD / 128)               // 391
#define CVTW_BLOCKS ((HIDN * FEAT / 4 + DD * HIDN / 4 + DD * DD / 4) / 256) // 148

using s16x8 = __attribute__((ext_vector_type(8))) short;
using f32x4 = __attribute__((ext_vector_type(4))) float;
using u32x4 = __attribute__((ext_vector_type(4))) unsigned int;

__device__ __forceinline__ unsigned short f2bf(float f){
  unsigned int u = __float_as_uint(f);
  unsigned int r = (u + 0x7fffu + ((u >> 16) & 1u)) >> 16;
  return (unsigned short)r;
}

__device__ __forceinline__ float bf2f(unsigned short s){
  unsigned int u = ((unsigned int)s) << 16;
  return __uint_as_float(u);
}

// packed f32x2 -> bf16x2 (RNE), gfx950 HW cvt [T12/m240]
__device__ __forceinline__ unsigned int cvtpk(float lo, float hi){
  unsigned int r;
  asm("v_cvt_pk_bf16_f32 %0, %1, %2" : "=v"(r) : "v"(lo), "v"(hi));
  return r;
}

__device__ __forceinline__ void gload_lds16(const void* g, void* l){
  __builtin_amdgcn_global_load_lds(
      (const __attribute__((address_space(1))) unsigned int*)g,
      (__attribute__((address_space(3))) unsigned int*)l, 16, 0, 0);
}

// ================= device bodies (packed kernels call these) =================

// ---- histo: per-chunk LDS histogram over 625 dst-buckets ----
__device__ __forceinline__ void dev_histo(int c, const int* __restrict__ ei,
                                          int* __restrict__ hist, int* h){
  const int tid = threadIdx.x;
  for (int i = tid; i < NBUCK; i += 256) h[i] = 0;
  __syncthreads();
  int e0 = c * CHSZ, e1 = min(e0 + CHSZ, NE);
  for (int e = e0 + tid; e < e1; e += 256)
    atomicAdd(&h[ei[NE + e] >> 7], 1);
  __syncthreads();
  for (int i = tid; i < NBUCK; i += 256) hist[i * NCHUNK + c] = h[i];
}

// ---- weights fp32 -> bf16 (w1 | w2 | cw only; feats stays f32) ----
__device__ __forceinline__ void dev_cvtw(int blk,
    const float* __restrict__ w1, const float* __restrict__ w2, const float* __restrict__ cw,
    unsigned short* __restrict__ w1b, unsigned short* __restrict__ w2b,
    unsigned short* __restrict__ cwb){
  const int n1 = HIDN * FEAT / 4, n2 = DD * HIDN / 4, n3 = DD * DD / 4;
  int q = blk * 256 + threadIdx.x;
  const float4* src; ushort4* dst; int i;
  if (q < n1){ src = (const float4*)w1; dst = (ushort4*)w1b; i = q; }
  else if (q < n1 + n2){ src = (const float4*)w2; dst = (ushort4*)w2b; i = q - n1; }
  else if (q < n1 + n2 + n3){ src = (const float4*)cw; dst = (ushort4*)cwb; i = q - n1 - n2; }
  else return;
  float4 v = src[i];
  ushort4 o = { f2bf(v.x), f2bf(v.y), f2bf(v.z), f2bf(v.w) };
  dst[i] = o;
}

// ---- GEMM1 (BM=64, BN=128, f32 A direct): hiddenb = bf16(leaky(feats @ w1b^T + b1)) ----
// R13-proven floor config: 1564 blocks, ~6 blocks/CU TLP; A staged f32 via
// global_load_lds with XOR-swizzled SOURCE chunk (kc^(row&7)), un-XOR on read,
// cvt_pk to bf16 at fragment time. Single-buffer 2-barrier K-loop.
__device__ __forceinline__ void dev_gemm1(int bx, int by,
    const float* __restrict__ feats, const short* __restrict__ w1b,
    const float* __restrict__ b1, unsigned short* __restrict__ hiddenb,
    float* Asf, short* Bs){
  const int tid  = threadIdx.x;
  const int wid  = tid >> 6;
  const int lane = tid & 63;
  const int wr   = wid >> 1;            // wave row (0..1): 32 rows each
  const int wc   = wid & 1;             // wave col (0..1): 64 cols each
  const int m0   = by * 64;
  const int n0   = bx * 128;

  f32x4 acc[2][4] = {};

  for (int k0 = 0; k0 < FEAT; k0 += 32){
    // A: 64 rows x 32 f32 = 512 x 16B chunks, 2 issues; swizzled global source
    #pragma unroll
    for (int s = 0; s < 2; s++){
      int q = s * 256 + tid;
      int row = q >> 3, kc = q & 7;
      int gr = m0 + row; if (gr >= NITEM) gr = NITEM - 1;   // clamp tail (stores masked)
      int kcs = kc ^ (row & 7);
      gload_lds16(&feats[(size_t)gr * FEAT + k0 + kcs * 4],
                  Asf + (size_t)(s * 256 + wid * 64) * 4);
    }
    // B: w1 tile 128x32 bf16 = 512 x 16B chunks, 2 issues
    #pragma unroll
    for (int s = 0; s < 2; s++){
      int q = s * 256 + tid;
      int row = q >> 2, kc = q & 3;
      gload_lds16(w1b + (size_t)(n0 + row) * FEAT + k0 + kc * 8,
                  Bs + (size_t)(s * 256 + wid * 64) * 8);
    }
    __syncthreads();

    s16x8 af[2], bf[4];
    #pragma unroll
    for (int m = 0; m < 2; m++){
      int r  = wr * 32 + m * 16 + (lane & 15);
      int c0 = (lane >> 4) * 2;
      const float4 v0 = *(const float4*)&Asf[r * 32 + ((c0    ) ^ (r & 7)) * 4];
      const float4 v1 = *(const float4*)&Asf[r * 32 + ((c0 + 1) ^ (r & 7)) * 4];
      u32x4 t;
      t[0] = cvtpk(v0.x, v0.y); t[1] = cvtpk(v0.z, v0.w);
      t[2] = cvtpk(v1.x, v1.y); t[3] = cvtpk(v1.z, v1.w);
      af[m] = *(s16x8*)&t;
    }
    #pragma unroll
    for (int n = 0; n < 4; n++)
      bf[n] = *(const s16x8*)&Bs[(wc * 64 + n * 16 + (lane & 15)) * 32 + (lane >> 4) * 8];
    #pragma unroll
    for (int m = 0; m < 2; m++)
      #pragma unroll
      for (int n = 0; n < 4; n++)
        acc[m][n] = __builtin_amdgcn_mfma_f32_16x16x32_bf16(af[m], bf[n], acc[m][n], 0, 0, 0);
    __syncthreads();
  }

  #pragma unroll
  for (int m = 0; m < 2; m++){
    int row_base = m0 + wr * 32 + m * 16 + (lane >> 4) * 4;
    #pragma unroll
    for (int n = 0; n < 4; n++){
      int col = n0 + wc * 64 + n * 16 + (lane & 15);
      float bi = b1[col];
      #pragma unroll
      for (int r = 0; r < 4; r++){
        int row = row_base + r;
        if (row >= NITEM) continue;
        float v = acc[m][n][r] + bi;
        v = v > 0.f ? v : 0.01f * v;
        hiddenb[(size_t)row * HIDN + col] = f2bf(v);
      }
    }
  }
}

// ---- scan_apply, 256-thread version (4 elems/thread) ----
__device__ __forceinline__ void dev_scan_apply4(int blk, const int* __restrict__ a,
                                                const int* __restrict__ boff,
                                                int* __restrict__ sc, int* wsum4){
  int tid = threadIdx.x;
  int base = blk * 1024 + tid * 4;
  int v0 = (base + 0 < NHIST) ? a[base + 0] : 0;
  int v1 = (base + 1 < NHIST) ? a[base + 1] : 0;
  int v2 = (base + 2 < NHIST) ? a[base + 2] : 0;
  int v3 = (base + 3 < NHIST) ? a[base + 3] : 0;
  int s = v0 + v1 + v2 + v3;
  int lane = tid & 63, w = tid >> 6;
  int incl = s;
  #pragma unroll
  for (int o = 1; o < 64; o <<= 1){ int u = __shfl_up(incl, o); if (lane >= o) incl += u; }
  if (lane == 63) wsum4[w] = incl;
  __syncthreads();
  int woff = 0;
  #pragma unroll
  for (int k = 0; k < 4; k++) if (k < w) woff += wsum4[k];
  int excl = boff[blk] + woff + incl - s;
  if (base + 0 < NHIST) sc[base + 0] = excl; excl += v0;
  if (base + 1 < NHIST) sc[base + 1] = excl; excl += v1;
  if (base + 2 < NHIST) sc[base + 2] = excl; excl += v2;
  if (base + 3 < NHIST) sc[base + 3] = excl;
}

// ---- GEMM2: x items = hiddenb @ w2b^T + b2 (f32 out) ----
__device__ __forceinline__ void dev_gemm2(int by,
    const short* __restrict__ Ag, const short* __restrict__ Bg,
    const float* __restrict__ bias, float* __restrict__ Cout,
    short* As, short* Bs){
  const int tid  = threadIdx.x;
  const int wid  = tid >> 6;
  const int lane = tid & 63;
  const int wr   = wid >> 1;
  const int wc   = wid & 1;
  const int m0   = by * 128;

  f32x4 acc[4][2] = {};

  for (int k0 = 0; k0 < HIDN; k0 += 32){
    #pragma unroll
    for (int s = 0; s < 2; s++){
      int q = s * 256 + tid;
      int row = q >> 2, kc = q & 3;
      const short* src = Ag + (size_t)(m0 + row) * HIDN + k0 + kc * 8;
      gload_lds16(src, As + (size_t)(s * 256 + wid * 64) * 8);
    }
    {
      int row = tid >> 2, kc = tid & 3;
      const short* src = Bg + (size_t)row * HIDN + k0 + kc * 8;
      gload_lds16(src, Bs + (size_t)(wid * 64) * 8);
    }
    __syncthreads();

    s16x8 af[4], bf[2];
    #pragma unroll
    for (int m = 0; m < 4; m++)
      af[m] = *(const s16x8*)&As[(wr * 64 + m * 16 + (lane & 15)) * 32 + (lane >> 4) * 8];
    #pragma unroll
    for (int n = 0; n < 2; n++)
      bf[n] = *(const s16x8*)&Bs[(wc * 32 + n * 16 + (lane & 15)) * 32 + (lane >> 4) * 8];
    #pragma unroll
    for (int m = 0; m < 4; m++)
      #pragma unroll
      for (int n = 0; n < 2; n++)
        acc[m][n] = __builtin_amdgcn_mfma_f32_16x16x32_bf16(af[m], bf[n], acc[m][n], 0, 0, 0);
    __syncthreads();
  }

  #pragma unroll
  for (int m = 0; m < 4; m++){
    int row_base = m0 + wr * 64 + m * 16 + (lane >> 4) * 4;
    #pragma unroll
    for (int n = 0; n < 2; n++){
      int col = wc * 32 + n * 16 + (lane & 15);
      float bi = bias[col];
      #pragma unroll
      for (int r = 0; r < 4; r++){
        int row = row_base + r;
        if (row >= NITEM) continue;
        Cout[(size_t)row * DD + col] = acc[m][n][r] + bi;
      }
    }
  }
}

// ---- binscat: LDS-cursor scatter of packed (dst&127)<<17 | src ----
__device__ __forceinline__ void dev_binscat(int c, const int* __restrict__ ei,
                                            const int* __restrict__ sc,
                                            int* __restrict__ pairsv, int* cur){
  const int tid = threadIdx.x;
  for (int i = tid; i < NBUCK; i += 256) cur[i] = sc[i * NCHUNK + c];
  __syncthreads();
  int e0 = c * CHSZ, e1 = min(e0 + CHSZ, NE);
  for (int e = e0 + tid; e < e1; e += 256){
    int s = ei[e];
    int d = ei[NE + e];
    int pos = atomicAdd(&cur[d >> 7], 1);
    pairsv[pos] = ((d & 127) << 17) | s;
  }
}

// ---- bucketize (fused count + scan + fill): fixed base = sc[b*NCHUNK] + 1024*b ----
__device__ __forceinline__ void dev_bucketize(int b,
    const int* __restrict__ pairsv, const int* __restrict__ sc,
    float* __restrict__ dinv, int* __restrict__ csr,
    int* __restrict__ indptr, int* __restrict__ nitv,
    int* cnt, int* cur, int* l0, int* wtot){
  const int tid = threadIdx.x;
  if (tid < 128) cnt[tid] = 0;
  __syncthreads();
  int e0 = sc[b * NCHUNK];
  int e1 = (b == NBUCK - 1) ? NE : sc[(b + 1) * NCHUNK];
  for (int e = e0 + tid; e < e1; e += 256)
    atomicAdd(&cnt[(pairsv[e] >> 17) & 127], 1);
  __syncthreads();
  int lane = tid & 63;
  int incl = 0, pc = 0, cdeg = 0;
  if (tid < 128){
    cdeg = cnt[tid];
    pc = (cdeg + 8) & ~7;            // deg + 1 self, padded to x8
    incl = pc;
    #pragma unroll
    for (int o = 1; o < 64; o <<= 1){ int u = __shfl_up(incl, o); if (lane >= o) incl += u; }
  }
  if (tid == 63) *wtot = incl;
  __syncthreads();
  if (tid < 128){
    int excl = incl - pc + (tid >= 64 ? *wtot : 0);
    cur[tid] = excl; l0[tid] = excl;
    dinv[b * 128 + tid] = rsqrtf((float)(cdeg + 1));
  }
  __syncthreads();
  const int base = e0 + 1024 * b;
  for (int e = e0 + tid; e < e1; e += 256){
    int v = pairsv[e];
    int li = (v >> 17) & 127;
    int p = atomicAdd(&cur[li], 1);
    csr[base + p] = v & 0x1FFFF;
  }
  __syncthreads();
  if (tid < 128){
    int node = b * 128 + tid;
    int c = cur[tid];                 // l0 + deg
    int l = l0[tid];
    int end = l + ((c - l + 8) & ~7);
    csr[base + c] = node;             // self-loop
    for (int q = c + 1; q < end; q++) csr[base + q] = NN;   // pads -> zero row
    indptr[node] = base + l;
    nitv[node] = (end - l) >> 3;      // padded count / 8
  }
}

// ---- normalize one 4-node block ----
__device__ __forceinline__ void dev_normalize(int nb, const float* __restrict__ pref,
                                              float* __restrict__ x){
  int node = nb * 4 + (threadIdx.x >> 6);
  int lane = threadIdx.x & 63;
  float v = (node < NUSER) ? pref[(size_t)node * DD + lane] : x[(size_t)node * DD + lane];
  float ss = v * v;
  #pragma unroll
  for (int o = 1; o < 64; o <<= 1) ss += __shfl_xor(ss, o);
  v = v / fmaxf(sqrtf(ss), 1e-12f);
  x[(size_t)node * DD + lane] = v;
}

// ================= packed kernels =================
__global__ __launch_bounds__(256) void p1_histo_cvtw(const int* __restrict__ ei,
    int* __restrict__ hist, const float* __restrict__ w1, const float* __restrict__ w2,
    const float* __restrict__ cw, unsigned short* __restrict__ w1b,
    unsigned short* __restrict__ w2b, unsigned short* __restrict__ cwb){
  __shared__ int h[NBUCK];
  int b = blockIdx.x;
  if (b < NCHUNK) dev_histo(b, ei, hist, h);
  else            dev_cvtw(b - NCHUNK, w1, w2, cw, w1b, w2b, cwb);
}

__global__ __launch_bounds__(256) void scan_part(const int* __restrict__ a,
                                                 int* __restrict__ bsum){
  __shared__ int ws4[4];
  int b = blockIdx.x, base = b * 1024;
  int v = 0;
  #pragma unroll
  for (int s = 0; s < 4; s++){
    int idx = base + s * 256 + threadIdx.x;
    if (idx < NHIST) v += a[idx];
  }
  int lane = threadIdx.x & 63, w = threadIdx.x >> 6;
  #pragma unroll
  for (int o = 1; o < 64; o <<= 1) v += __shfl_xor(v, o);
  if (lane == 0) ws4[w] = v;
  __syncthreads();
  if (threadIdx.x == 0) bsum[b] = ws4[0] + ws4[1] + ws4[2] + ws4[3];
}

__global__ __launch_bounds__(1024) void scan_mid(const int* __restrict__ a,
                                                 int* __restrict__ excl_out){
  __shared__ int wsum[16];
  int tid = threadIdx.x;
  int v = (tid < NPART) ? a[tid] : 0;
  int lane = tid & 63, w = tid >> 6;
  int incl = v;
  #pragma unroll
  for (int o = 1; o < 64; o <<= 1){ int u = __shfl_up(incl, o); if (lane >= o) incl += u; }
  if (lane == 63) wsum[w] = incl;
  __syncthreads();
  int woff = 0;
  #pragma unroll
  for (int k = 0; k < 16; k++) if (k < w) woff += wsum[k];
  if (tid < NPART) excl_out[tid] = woff + incl - v;
}

__global__ __launch_bounds__(256) void p2_gemm1_scan(const float* __restrict__ feats,
    const short* __restrict__ w1b, const float* __restrict__ b1,
    unsigned short* __restrict__ hiddenb, const int* __restrict__ hist,
    const int* __restrict__ boff, int* __restrict__ sc){
  __shared__ __align__(16) float Asf[64 * 32];    // 8KB
  __shared__ __align__(16) short Bs[128 * 32];    // 8KB
  __shared__ int wsum4[4];
  int b = blockIdx.x;
  if (b < G1_BLOCKS) dev_gemm1(b & 1, b >> 1, feats, w1b, b1, hiddenb, Asf, Bs);
  else               dev_scan_apply4(b - G1_BLOCKS, hist, boff, sc, wsum4);
}

__global__ __launch_bounds__(256) void p3_gemm2_binscat(const unsigned short* __restrict__ hiddenb,
    const short* __restrict__ w2b, const float* __restrict__ b2, float* __restrict__ xitems,
    const int* __restrict__ ei, const int* __restrict__ sc, int* __restrict__ pairsv){
  __shared__ __align__(16) short As[128 * 32];    // 8KB
  __shared__ __align__(16) short Bs[64 * 32];     // 4KB
  __shared__ int cur[NBUCK];                      // 2.5KB
  int b = blockIdx.x;
  if (b < G2_BLOCKS) dev_gemm2(b, (const short*)hiddenb, w2b, b2, xitems, As, Bs);
  else               dev_binscat(b - G2_BLOCKS, ei, sc, pairsv, cur);
}

__global__ __launch_bounds__(256) void p4_bucketize_norm(const int* __restrict__ pairsv,
    const int* __restrict__ sc, float* __restrict__ dinv, int* __restrict__ csr,
    int* __restrict__ indptr, int* __restrict__ nitv,
    const float* __restrict__ pref, float* __restrict__ x){
  __shared__ int cnt[128], cur[128], l0[128];
  __shared__ int wtot;
  int b = blockIdx.x;
  if (b < NBUCK) dev_bucketize(b, pairsv, sc, dinv, csr, indptr, nitv, cnt, cur, l0, &wtot);
  else           dev_normalize(b - NBUCK, pref, x);
}

// ---------------- lin via MFMA: hsb = bf16(dinv[row] * (src @ cwb^T)) ----------------
// block 0 additionally zeroes the pad row hsb[NN] (replaces a memset launch).
__global__ __launch_bounds__(256) void lin_mfma(const float* __restrict__ src,
                                                const short* __restrict__ cwb,
                                                const float* __restrict__ dinv,
                                                unsigned short* __restrict__ hsb){
  constexpr int AP = 72;                        // padded stride (elems)
  __shared__ __align__(16) short As[128 * AP];  // 18KB

  const int tid  = threadIdx.x;
  const int wid  = tid >> 6;
  const int lane = tid & 63;
  const int wr   = wid >> 1;
  const int wc   = wid & 1;
  const int m0   = blockIdx.x * 128;

  if (blockIdx.x == 0 && tid < 16)
    *(unsigned long long*)&hsb[(size_t)NN * DD + tid * 4] = 0ULL;  // 128B pad row

  #pragma unroll
  for (int s = 0; s < 8; s++){
    int c = s * 256 + tid;
    int row = c >> 4, kc = c & 15;
    float4 v = *(const float4*)&src[(size_t)(m0 + row) * DD + kc * 4];
    ushort4 o = { f2bf(v.x), f2bf(v.y), f2bf(v.z), f2bf(v.w) };
    *(ushort4*)&As[row * AP + kc * 4] = o;
  }
  __syncthreads();

  f32x4 acc[4][2] = {};
  #pragma unroll
  for (int kk = 0; kk < DD; kk += 32){
    s16x8 af[4], bf[2];
    #pragma unroll
    for (int m = 0; m < 4; m++)
      af[m] = *(const s16x8*)&As[(wr * 64 + m * 16 + (lane & 15)) * AP + kk + (lane >> 4) * 8];
    #pragma unroll
    for (int n = 0; n < 2; n++)
      bf[n] = *(const s16x8*)&cwb[(size_t)(wc * 32 + n * 16 + (lane & 15)) * DD + kk + (lane >> 4) * 8];
    #pragma unroll
    for (int m = 0; m < 4; m++)
      #pragma unroll
      for (int n = 0; n < 2; n++)
        acc[m][n] = __builtin_amdgcn_mfma_f32_16x16x32_bf16(af[m], bf[n], acc[m][n], 0, 0, 0);
  }

  #pragma unroll
  for (int m = 0; m < 4; m++){
    int row_base = m0 + wr * 64 + m * 16 + (lane >> 4) * 4;
    #pragma unroll
    for (int n = 0; n < 2; n++){
      int col = wc * 32 + n * 16 + (lane & 15);
      #pragma unroll
      for (int r = 0; r < 4; r++){
        int row = row_base + r;
        hsb[(size_t)row * DD + col] = f2bf(dinv[row] * acc[m][n][r]);
      }
    }
  }
}

// ---------------- gather aggregation: 8 edges in flight, 8 lanes x s16x8 ----------------
template<int FINAL>
__global__ __launch_bounds__(256) void agg_kernel(const unsigned short* __restrict__ hsb,
                                                  const float* __restrict__ dinv,
                                                  const int* __restrict__ indptr,
                                                  const int* __restrict__ nitv,
                                                  const int* __restrict__ csr,
                                                  const float* __restrict__ bias,
                                                  const float* __restrict__ x,
                                                  const float* __restrict__ h,
                                                  float* __restrict__ out,
                                                  const float* __restrict__ pref,
                                                  float* __restrict__ out2){
  int b = blockIdx.x;
  if (FINAL && b >= NN / 4){
    long q = (long)(b - NN / 4) * 256 + threadIdx.x;
    if (q < (long)NUSER * DD / 4)
      ((float4*)out2)[q] = ((const float4*)pref)[q];
    return;
  }
  int node = b * 4 + (threadIdx.x >> 6);
  int lane = threadIdx.x & 63;
  int g  = lane >> 3;
  int sl = lane & 7;
  int e0 = indptr[node];
  int nit = nitv[node];
  float a0=0.f,a1=0.f,a2=0.f,a3=0.f,a4=0.f,a5=0.f,a6=0.f,a7=0.f;
  int k = e0 + g;
  for (int i = 0; i < nit; i++){
    int j = csr[k];
    k += 8;
    s16x8 v = *(const s16x8*)&hsb[(size_t)j * DD + sl * 8];
    a0 += bf2f((unsigned short)v[0]); a1 += bf2f((unsigned short)v[1]);
    a2 += bf2f((unsigned short)v[2]); a3 += bf2f((unsigned short)v[3]);
    a4 += bf2f((unsigned short)v[4]); a5 += bf2f((unsigned short)v[5]);
    a6 += bf2f((unsigned short)v[6]); a7 += bf2f((unsigned short)v[7]);
  }
  #pragma unroll
  for (int off = 8; off < 64; off <<= 1){
    a0 += __shfl_xor(a0, off); a1 += __shfl_xor(a1, off);
    a2 += __shfl_xor(a2, off); a3 += __shfl_xor(a3, off);
    a4 += __shfl_xor(a4, off); a5 += __shfl_xor(a5, off);
    a6 += __shfl_xor(a6, off); a7 += __shfl_xor(a7, off);
  }
  if (g == 0){
    float di = dinv[node];
    size_t rb = (size_t)node * DD + sl * 8;
    const float4 bi0 = *(const float4*)&bias[sl * 8];
    const float4 bi1 = *(const float4*)&bias[sl * 8 + 4];
    float4 r0, r1;
    r0.x = fmaf(di, a0, bi0.x); r0.y = fmaf(di, a1, bi0.y);
    r0.z = fmaf(di, a2, bi0.z); r0.w = fmaf(di, a3, bi0.w);
    r1.x = fmaf(di, a4, bi1.x); r1.y = fmaf(di, a5, bi1.y);
    r1.z = fmaf(di, a6, bi1.z); r1.w = fmaf(di, a7, bi1.w);
    if (FINAL){
      const float4 xv0 = *(const float4*)&x[rb];
      const float4 xv1 = *(const float4*)&x[rb + 4];
      const float4 hv0 = *(const float4*)&h[rb];
      const float4 hv1 = *(const float4*)&h[rb + 4];
      r0.x += xv0.x + hv0.x; r0.y += xv0.y + hv0.y;
      r0.z += xv0.z + hv0.z; r0.w += xv0.w + hv0.w;
      r1.x += xv1.x + hv1.x; r1.y += xv1.y + hv1.y;
      r1.z += xv1.z + hv1.z; r1.w += xv1.w + hv1.w;
    }
    *(float4*)&out[rb] = r0;
    *(float4*)&out[rb + 4] = r1;
  }
}

extern "C" void kernel_launch(void* const* d_in, const int* in_sizes, int n_in,
                              void* d_out, int out_size, void* d_ws, size_t ws_size,
                              hipStream_t stream){
  const int*   ei    = (const int*)  d_in[0];
  const float* feats = (const float*)d_in[1];
  const float* pref  = (const float*)d_in[2];
  const float* w1    = (const float*)d_in[3];
  const float* b1    = (const float*)d_in[4];
  const float* w2    = (const float*)d_in[5];
  const float* b2    = (const float*)d_in[6];
  const float* cw    = (const float*)d_in[7];
  const float* cb    = (const float*)d_in[8];
  float* out = (float*)d_out;

  // ---- workspace layout (lifetime-overlapped; peak ~77.2MB, proven) ----
  // [0, 20.48MB)      x f32 [NN*64]
  // [20.48, 40.96MB)  hbuf f32 [NN*64] -- CSR scratch (pairsv|hist|sc|bsum|boff) overlays
  //                   it until bucketize; hbuf written by agg0 afterwards
  // [40.96, ~49.3MB)  live graph: csr[CSRCAP] | indptr[NN] | nitv[NN] | dinv[NN]
  // [51.25, 76.9MB)   hiddenb bf16 [MPAD*256] (dead after gemm2), overlaid by hsb_a | hsb_b
  // [76.9, ~77.5MB)   w1b, w2b, cwb bf16
  char* wsb = (char*)d_ws;
  float* x       = (float*)wsb;
  float* hbuf    = (float*)(wsb + (size_t)NN * DD * 4);
  int*   pairsv  = (int*)hbuf;
  int*   hist    = pairsv + NE;
  int*   sc      = hist + NHIST;
  int*   bsum    = sc + NHIST;
  int*   boff    = bsum + NPART;
  char*  graphb  = wsb + (size_t)NN * DD * 8;
  int*   csr     = (int*)graphb;
  int*   indptr  = csr + CSRCAP;
  int*   nitv    = indptr + NN;
  float* dinv    = (float*)(nitv + NN);
  unsigned short* hiddenb = (unsigned short*)(wsb + (size_t)MPAD * FEAT * 2);
  unsigned short* hsba = hiddenb;
  unsigned short* hsbb = hsba + (size_t)(NN + 1) * DD;
  short* w1b     = (short*)(wsb + (size_t)MPAD * FEAT * 2 + (size_t)(MPAD + 64) * HIDN * 2);
  short* w2b     = w1b + (size_t)HIDN * FEAT;
  short* cwb     = w2b + (size_t)DD * HIDN;

  // ---- P1: edge histogram ∪ weight cvt ----
  p1_histo_cvtw<<<NCHUNK + CVTW_BLOCKS, 256, 0, stream>>>(
      ei, hist, w1, w2, cw, (unsigned short*)w1b, (unsigned short*)w2b,
      (unsigned short*)cwb);
  // ---- hist scan (part -> mid) ----
  scan_part<<<NPART, 256, 0, stream>>>(hist, bsum);
  scan_mid<<<1, 1024, 0, stream>>>(bsum, boff);
  // ---- P2: GEMM1 (BM=64, f32 A direct, high-TLP) ∪ scan_apply ----
  p2_gemm1_scan<<<G1_BLOCKS + NPART, 256, 0, stream>>>(
      feats, w1b, b1, hiddenb, hist, boff, sc);
  // ---- P3: GEMM2 ∪ binscat ----
  p3_gemm2_binscat<<<G2_BLOCKS + NCHUNK, 256, 0, stream>>>(
      hiddenb, w2b, b2, x + (size_t)NUSER * DD, ei, sc, pairsv);
  // ---- P4: bucketize (fused count+scan+fill) ∪ normalize ----
  p4_bucketize_norm<<<NBUCK + NN / 4, 256, 0, stream>>>(
      pairsv, sc, dinv, csr, indptr, nitv, pref, x);

  // ---- conv1: lin (+ zero hsba pad row) + gather ----
  lin_mfma<<<NN / 128, 256, 0, stream>>>(x, cwb, dinv, hsba);
  agg_kernel<0><<<NN / 4, 256, 0, stream>>>(hsba, dinv, indptr, nitv, csr, cb,
                                            nullptr, nullptr, hbuf, nullptr, nullptr);
  // ---- conv2: lin (+ zero hsbb pad row) + gather + residual + pref tail ----
  lin_mfma<<<NN / 128, 256, 0, stream>>>(hbuf, cwb, dinv, hsbb);
  agg_kernel<1><<<NN / 4 + (NUSER * DD / 4) / 256, 256, 0, stream>>>(
      hsbb, dinv, indptr, nitv, csr, cb, x, hbuf, out, pref, out + (size_t)NN * DD);
}